// Round 1
// 1090.276 us; speedup vs baseline: 1.0225x; 1.0225x over previous
//
#include <hip/hip_runtime.h>
#include <hip/hip_fp16.h>

// Sinkhorn, 64 x 1024 x 1024 fp32, 20 iterations.
//
// Linear-domain identity: K = exp(-C/eps); u = 1/(K v); v = 1/(K^T u);
// out = u_i K_ij v_j.
//
// K cached as fp16 in d_ws (134 MB, L3-resident). Wave-per-row layout:
// each 64-lane wave owns a full 1024-col row (16 halves/lane, 2x uint4
// loads), so the row sum is a single 6-step in-wave butterfly -- no LDS,
// no __syncthreads in the main loop. Column partials accumulate in 16
// registers/lane; the block's 4 waves combine once per kernel via 16 KB
// LDS, then 4 atomics/thread into the ping-pong colsum buffers.
// Falls back to the all-fp32 path if ws_size is too small.

#define BATCH 64
#define N 1024
#define NITERS 20
#define ROWS_PER_BLOCK 64
#define BLOCKS_PER_BATCH (N / ROWS_PER_BLOCK)  // 16
#define THREADS 256
#define NU2 (N / 4)  // uint2 (4 halves) per row = 256
#define NU4 (N / 8)  // uint4 (8 halves) per row = 128

// ---------- fp16 pack/unpack helpers ----------
union H2U { __half2 h; unsigned u; };

__device__ __forceinline__ uint2 f4_to_h4(float4 f) {
    H2U a, b;
    a.h = __float22half2_rn(make_float2(f.x, f.y));
    b.h = __float22half2_rn(make_float2(f.z, f.w));
    uint2 r; r.x = a.u; r.y = b.u;
    return r;
}

__device__ __forceinline__ float4 h4_to_f4(uint2 r) {
    H2U a, b;
    a.u = r.x; b.u = r.y;
    float2 fa = __half22float2(a.h);
    float2 fb = __half22float2(b.h);
    return make_float4(fa.x, fa.y, fb.x, fb.y);
}

__device__ __forceinline__ void h8_unpack(uint4 r, float* f) {
    H2U a, b, c, d;
    a.u = r.x; b.u = r.y; c.u = r.z; d.u = r.w;
    float2 fa = __half22float2(a.h), fb = __half22float2(b.h);
    float2 fc = __half22float2(c.h), fd = __half22float2(d.h);
    f[0] = fa.x; f[1] = fa.y; f[2] = fb.x; f[3] = fb.y;
    f[4] = fc.x; f[5] = fc.y; f[6] = fd.x; f[7] = fd.y;
}

__device__ __forceinline__ uint4 h8_pack(const float* f) {
    H2U a, b, c, d;
    a.h = __float22half2_rn(make_float2(f[0], f[1]));
    b.h = __float22half2_rn(make_float2(f[2], f[3]));
    c.h = __float22half2_rn(make_float2(f[4], f[5]));
    d.h = __float22half2_rn(make_float2(f[6], f[7]));
    uint4 r; r.x = a.u; r.y = b.u; r.z = c.u; r.w = d.u;
    return r;
}

// ---------- cached-K path ----------

// zero the 20 colsum ping-pong buffers
__global__ __launch_bounds__(THREADS) void sk_zero(float* __restrict__ csum_all) {
    const int i = blockIdx.x * THREADS + threadIdx.x;
    csum_all[i] = 0.0f;
}

// Iteration 1 fused with K construction. v = 1 (no csum_in).
// Wave-per-row: wave w handles rows [row0 + w*16, row0 + w*16 + 16).
__global__ __launch_bounds__(THREADS) void sk_build(
        const float* __restrict__ C, const float* __restrict__ eps,
        uint4* __restrict__ K, float* __restrict__ u,
        float* __restrict__ csum_out) {
    __shared__ float4 smc[4][N / 4];  // 16 KB: per-wave column partials
    const int t = threadIdx.x;
    const int lane = t & 63, w = t >> 6;
    const int b = blockIdx.y;
    const int row0 = blockIdx.x * ROWS_PER_BLOCK + w * 16;
    const float nie = -1.0f / eps[0];

    const float4* __restrict__ Cp =
        (const float4*)(C + ((size_t)b * N + row0) * N) + lane * 4;
    uint4* __restrict__ Kp = K + ((size_t)b * N + row0) * NU4 + lane * 2;

    float colacc[16];
    #pragma unroll
    for (int q = 0; q < 16; ++q) colacc[q] = 0.0f;

    float4 cur[4];
    #pragma unroll
    for (int q = 0; q < 4; ++q) cur[q] = Cp[q];

    for (int i = 0; i < 16; ++i) {
        float4 nxt[4];
        if (i < 15) {
            #pragma unroll
            for (int q = 0; q < 4; ++q) nxt[q] = Cp[(i + 1) * (N / 4) + q];
        }
        float k[16];
        const float* cf = (const float*)cur;
        #pragma unroll
        for (int q = 0; q < 16; ++q) k[q] = __expf(cf[q] * nie);

        Kp[(size_t)i * NU4]     = h8_pack(k);
        Kp[(size_t)i * NU4 + 1] = h8_pack(k + 8);

        // row sum (v = 1), balanced tree
        float s = (((k[0] + k[1]) + (k[2] + k[3])) + ((k[4] + k[5]) + (k[6] + k[7])))
                + (((k[8] + k[9]) + (k[10] + k[11])) + ((k[12] + k[13]) + (k[14] + k[15])));
        #pragma unroll
        for (int off = 32; off; off >>= 1) s += __shfl_xor(s, off, 64);
        const float ui = 1.0f / s;
        if (lane == 0) u[b * N + row0 + i] = ui;

        #pragma unroll
        for (int q = 0; q < 16; ++q) colacc[q] += k[q] * ui;

        if (i < 15) {
            #pragma unroll
            for (int q = 0; q < 4; ++q) cur[q] = nxt[q];
        }
    }

    // combine the 4 waves' column partials, one atomic pass per block
    #pragma unroll
    for (int q = 0; q < 4; ++q)
        smc[w][lane * 4 + q] = make_float4(colacc[4 * q], colacc[4 * q + 1],
                                           colacc[4 * q + 2], colacc[4 * q + 3]);
    __syncthreads();
    float4 s0 = smc[0][t], s1 = smc[1][t], s2 = smc[2][t], s3 = smc[3][t];
    float4 sum;
    sum.x = (s0.x + s1.x) + (s2.x + s3.x);
    sum.y = (s0.y + s1.y) + (s2.y + s3.y);
    sum.z = (s0.z + s1.z) + (s2.z + s3.z);
    sum.w = (s0.w + s1.w) + (s2.w + s3.w);
    float* cs = csum_out + b * N + 4 * t;
    atomicAdd(cs + 0, sum.x);
    atomicAdd(cs + 1, sum.y);
    atomicAdd(cs + 2, sum.z);
    atomicAdd(cs + 3, sum.w);
}

// One Sinkhorn iteration from fp16 K. v = 1/csum_in (inverted on load).
__global__ __launch_bounds__(THREADS) void sk_iter(
        const uint4* __restrict__ K, const float* __restrict__ csum_in,
        float* __restrict__ u, float* __restrict__ csum_out) {
    __shared__ float4 smc[4][N / 4];  // 16 KB
    const int t = threadIdx.x;
    const int lane = t & 63, w = t >> 6;
    const int b = blockIdx.y;
    const int row0 = blockIdx.x * ROWS_PER_BLOCK + w * 16;

    // v for this lane's 16 columns
    const float4* __restrict__ cin = (const float4*)(csum_in + b * N) + lane * 4;
    float vv[16];
    #pragma unroll
    for (int q = 0; q < 4; ++q) {
        float4 c = cin[q];
        vv[4 * q + 0] = 1.0f / c.x;
        vv[4 * q + 1] = 1.0f / c.y;
        vv[4 * q + 2] = 1.0f / c.z;
        vv[4 * q + 3] = 1.0f / c.w;
    }

    const uint4* __restrict__ Kp = K + ((size_t)b * N + row0) * NU4 + lane * 2;

    float colacc[16];
    #pragma unroll
    for (int q = 0; q < 16; ++q) colacc[q] = 0.0f;

    uint4 c0 = Kp[0], c1 = Kp[1];
    for (int i = 0; i < 16; ++i) {
        uint4 n0, n1;
        if (i < 15) {
            n0 = Kp[(size_t)(i + 1) * NU4];
            n1 = Kp[(size_t)(i + 1) * NU4 + 1];
        }
        float k[16];
        h8_unpack(c0, k);
        h8_unpack(c1, k + 8);

        // dot(k, vv), balanced tree (fma-fused by compiler)
        float pa = (k[0] * vv[0] + k[1] * vv[1]) + (k[2] * vv[2] + k[3] * vv[3]);
        float pb = (k[4] * vv[4] + k[5] * vv[5]) + (k[6] * vv[6] + k[7] * vv[7]);
        float pc = (k[8] * vv[8] + k[9] * vv[9]) + (k[10] * vv[10] + k[11] * vv[11]);
        float pd = (k[12] * vv[12] + k[13] * vv[13]) + (k[14] * vv[14] + k[15] * vv[15]);
        float s = (pa + pb) + (pc + pd);

        #pragma unroll
        for (int off = 32; off; off >>= 1) s += __shfl_xor(s, off, 64);
        const float ui = 1.0f / s;
        if (lane == 0) u[b * N + row0 + i] = ui;

        #pragma unroll
        for (int q = 0; q < 16; ++q) colacc[q] += k[q] * ui;

        if (i < 15) { c0 = n0; c1 = n1; }
    }

    #pragma unroll
    for (int q = 0; q < 4; ++q)
        smc[w][lane * 4 + q] = make_float4(colacc[4 * q], colacc[4 * q + 1],
                                           colacc[4 * q + 2], colacc[4 * q + 3]);
    __syncthreads();
    float4 s0 = smc[0][t], s1 = smc[1][t], s2 = smc[2][t], s3 = smc[3][t];
    float4 sum;
    sum.x = (s0.x + s1.x) + (s2.x + s3.x);
    sum.y = (s0.y + s1.y) + (s2.y + s3.y);
    sum.z = (s0.z + s1.z) + (s2.z + s3.z);
    sum.w = (s0.w + s1.w) + (s2.w + s3.w);
    float* cs = csum_out + b * N + 4 * t;
    atomicAdd(cs + 0, sum.x);
    atomicAdd(cs + 1, sum.y);
    atomicAdd(cs + 2, sum.z);
    atomicAdd(cs + 3, sum.w);
}

__global__ __launch_bounds__(THREADS) void sk_final(
        const uint2* __restrict__ K, const float* __restrict__ u,
        const float* __restrict__ csum_last, float* __restrict__ out) {
    const int t = threadIdx.x;
    const int row = blockIdx.x;
    const int b = blockIdx.y;
    const float ui = u[b * N + row];
    const float4 ci = ((const float4*)(csum_last + b * N))[t];
    const float4 vv = make_float4(1.0f / ci.x, 1.0f / ci.y, 1.0f / ci.z, 1.0f / ci.w);
    const size_t base = (size_t)b * N + row;
    float4 k = h4_to_f4((K + base * NU2)[t]);
    float4 o;
    o.x = k.x * ui * vv.x;
    o.y = k.y * ui * vv.y;
    o.z = k.z * ui * vv.z;
    o.w = k.w * ui * vv.w;
    ((float4*)(out + base * N))[t] = o;
}

// ---------- fallback all-fp32 path (round-1, known-good) ----------

__device__ __forceinline__ float block_reduce_broadcast(float val, float* lds) {
    #pragma unroll
    for (int off = 32; off > 0; off >>= 1)
        val += __shfl_xor(val, off, 64);
    const int lane = threadIdx.x & 63;
    const int wid  = threadIdx.x >> 6;
    if (lane == 0) lds[wid] = val;
    __syncthreads();
    float total = lds[0] + lds[1] + lds[2] + lds[3];
    __syncthreads();
    return total;
}

__global__ __launch_bounds__(THREADS) void sink_init(float* __restrict__ v,
                                                     float* __restrict__ colsum) {
    const int i = blockIdx.x * THREADS + threadIdx.x;
    v[i] = 1.0f;
    colsum[i] = 0.0f;
}

__global__ __launch_bounds__(THREADS) void sink_iter(
        const float* __restrict__ C, const float* __restrict__ eps,
        const float* __restrict__ v, float* __restrict__ u,
        float* __restrict__ colsum) {
    __shared__ float lds[4];
    const int t = threadIdx.x;
    const int b = blockIdx.y;
    const int row0 = blockIdx.x * ROWS_PER_BLOCK;
    const float neg_inv_eps = -1.0f / eps[0];

    const float4 vv = ((const float4*)(v + b * N))[t];
    const float4* __restrict__ Cp = (const float4*)(C + ((size_t)b * N + row0) * N);

    float4 colacc = make_float4(0.f, 0.f, 0.f, 0.f);
    float4 cur = Cp[t];
    for (int i = 0; i < ROWS_PER_BLOCK; ++i) {
        float4 nxt = cur;
        if (i + 1 < ROWS_PER_BLOCK)
            nxt = Cp[(size_t)(i + 1) * (N / 4) + t];

        float4 k;
        k.x = __expf(cur.x * neg_inv_eps);
        k.y = __expf(cur.y * neg_inv_eps);
        k.z = __expf(cur.z * neg_inv_eps);
        k.w = __expf(cur.w * neg_inv_eps);

        float s = k.x * vv.x + k.y * vv.y + k.z * vv.z + k.w * vv.w;
        float S = block_reduce_broadcast(s, lds);
        float ui = 1.0f / S;
        if (t == 0) u[b * N + row0 + i] = ui;

        colacc.x += k.x * ui;
        colacc.y += k.y * ui;
        colacc.z += k.z * ui;
        colacc.w += k.w * ui;
        cur = nxt;
    }

    float* cs = colsum + b * N + 4 * t;
    atomicAdd(cs + 0, colacc.x);
    atomicAdd(cs + 1, colacc.y);
    atomicAdd(cs + 2, colacc.z);
    atomicAdd(cs + 3, colacc.w);
}

__global__ __launch_bounds__(THREADS) void sink_fix(float* __restrict__ v,
                                                    float* __restrict__ colsum) {
    const int i = blockIdx.x * THREADS + threadIdx.x;
    v[i] = 1.0f / colsum[i];
    colsum[i] = 0.0f;
}

__global__ __launch_bounds__(THREADS) void sink_final(
        const float* __restrict__ C, const float* __restrict__ eps,
        const float* __restrict__ u, const float* __restrict__ v,
        float* __restrict__ out) {
    const int t = threadIdx.x;
    const int row = blockIdx.x;
    const int b = blockIdx.y;
    const float neg_inv_eps = -1.0f / eps[0];
    const float ui = u[b * N + row];
    const float4 vv = ((const float4*)(v + b * N))[t];
    const size_t base = ((size_t)b * N + row) * N;
    float4 c = ((const float4*)(C + base))[t];
    float4 o;
    o.x = __expf(c.x * neg_inv_eps) * ui * vv.x;
    o.y = __expf(c.y * neg_inv_eps) * ui * vv.y;
    o.z = __expf(c.z * neg_inv_eps) * ui * vv.z;
    o.w = __expf(c.w * neg_inv_eps) * ui * vv.w;
    ((float4*)(out + base))[t] = o;
}

// ---------- launch ----------

extern "C" void kernel_launch(void* const* d_in, const int* in_sizes, int n_in,
                              void* d_out, int out_size, void* d_ws, size_t ws_size,
                              hipStream_t stream) {
    const float* C   = (const float*)d_in[0];
    const float* eps = (const float*)d_in[1];
    float* out = (float*)d_out;

    const size_t k_bytes  = (size_t)BATCH * N * N * 2;        // fp16 K: 134 MB
    const size_t uv_elems = (size_t)BATCH * N;                // 64K floats
    const size_t needed   = k_bytes + uv_elems * 4 * (1 + NITERS);

    if (ws_size >= needed) {
        uint4* K      = (uint4*)d_ws;
        float* u      = (float*)((char*)d_ws + k_bytes);
        float* csum   = u + uv_elems;  // 20 buffers of 64K floats, csum[t-1] for iter t

        // zero all 20 colsum buffers (ws is poisoned 0xAA before every call)
        sk_zero<<<dim3(NITERS * uv_elems / THREADS), dim3(THREADS), 0, stream>>>(csum);
        // iteration 1 fused with K build (v = 1)
        sk_build<<<dim3(BLOCKS_PER_BATCH, BATCH), dim3(THREADS), 0, stream>>>(
            C, eps, K, u, csum);
        // iterations 2..20
        for (int it = 2; it <= NITERS; ++it) {
            sk_iter<<<dim3(BLOCKS_PER_BATCH, BATCH), dim3(THREADS), 0, stream>>>(
                K, csum + (size_t)(it - 2) * uv_elems, u,
                csum + (size_t)(it - 1) * uv_elems);
        }
        sk_final<<<dim3(N, BATCH), dim3(THREADS), 0, stream>>>(
            (const uint2*)K, u, csum + (size_t)(NITERS - 1) * uv_elems, out);
    } else {
        // fallback: all-fp32 path
        float* u      = (float*)d_ws;
        float* v      = u + uv_elems;
        float* colsum = v + uv_elems;
        sink_init<<<dim3(BATCH * N / THREADS), dim3(THREADS), 0, stream>>>(v, colsum);
        for (int it = 0; it < NITERS; ++it) {
            sink_iter<<<dim3(BLOCKS_PER_BATCH, BATCH), dim3(THREADS), 0, stream>>>(
                C, eps, v, u, colsum);
            sink_fix<<<dim3(BATCH * N / THREADS), dim3(THREADS), 0, stream>>>(v, colsum);
        }
        sink_final<<<dim3(N, BATCH), dim3(THREADS), 0, stream>>>(C, eps, u, v, out);
    }
}

// Round 2
// 1006.098 us; speedup vs baseline: 1.1080x; 1.0837x over previous
//
#include <hip/hip_runtime.h>
#include <hip/hip_fp16.h>

// Sinkhorn, 64 x 1024 x 1024 fp32, 20 iterations.
//
// Linear-domain identity: K = exp(-C/eps); u = 1/(K v); v = 1/(K^T u);
// out = u_i K_ij v_j.
//
// Evidence so far: iter sweeps are byte-bound on the K fetch path
// (~2.8 TB/s effective from L3), not VALU/reduction-bound. So:
//  - build: read C, write K16 (fp16, 134 MB) AND K8 (fp8 e4m3, 67 MB),
//    fused with iteration 1 (v = 1, exact fp32 k for the sums)
//  - iterations 2..19: fp8 K sweeps (half the bytes). u,v are the fixed
//    point of stored K, and quantization error averages out over the
//    1024-element row/col sums (~0.1% systematic), decaying under
//    Sinkhorn contraction.
//  - iteration 20 + final product: fp16 K, so the output is exactly
//    row/col-normalized w.r.t. K16 (keeps absmax at the fp16 level).
// Wave-per-row layout everywhere: one 64-lane wave owns a full row; row
// sum is one 6-step butterfly, no LDS/barriers in the main loop. Column
// partials combine once per block via 16 KB LDS, then 4 atomics/thread
// into 20 pre-zeroed ping-pong colsum buffers.
// Falls back to the all-fp32 path if ws_size is too small.

#define BATCH 64
#define N 1024
#define NITERS 20
#define ROWS_PER_BLOCK 64
#define BLOCKS_PER_BATCH (N / ROWS_PER_BLOCK)  // 16
#define THREADS 256
#define NU2 (N / 4)     // uint2 (4 halves) per fp16 row = 256
#define NU4 (N / 8)     // uint4 (8 halves) per fp16 row = 128
#define NU4F8 (N / 16)  // uint4 (16 fp8) per fp8 row = 64

typedef float f32x2 __attribute__((ext_vector_type(2)));

// ---------- fp16 pack/unpack helpers ----------
union H2U { __half2 h; unsigned u; };

__device__ __forceinline__ float4 h4_to_f4(uint2 r) {
    H2U a, b;
    a.u = r.x; b.u = r.y;
    float2 fa = __half22float2(a.h);
    float2 fb = __half22float2(b.h);
    return make_float4(fa.x, fa.y, fb.x, fb.y);
}

__device__ __forceinline__ void h8_unpack(uint4 r, float* f) {
    H2U a, b, c, d;
    a.u = r.x; b.u = r.y; c.u = r.z; d.u = r.w;
    float2 fa = __half22float2(a.h), fb = __half22float2(b.h);
    float2 fc = __half22float2(c.h), fd = __half22float2(d.h);
    f[0] = fa.x; f[1] = fa.y; f[2] = fb.x; f[3] = fb.y;
    f[4] = fc.x; f[5] = fc.y; f[6] = fd.x; f[7] = fd.y;
}

__device__ __forceinline__ uint4 h8_pack(const float* f) {
    H2U a, b, c, d;
    a.h = __float22half2_rn(make_float2(f[0], f[1]));
    b.h = __float22half2_rn(make_float2(f[2], f[3]));
    c.h = __float22half2_rn(make_float2(f[4], f[5]));
    d.h = __float22half2_rn(make_float2(f[6], f[7]));
    uint4 r; r.x = a.u; r.y = b.u; r.z = c.u; r.w = d.u;
    return r;
}

// ---------- fp8 (OCP e4m3) pack/unpack via gfx950 HW cvt ----------
__device__ __forceinline__ uint4 pack_fp8_16(const float* k) {
    uint4 r;
    int a;
    a = __builtin_amdgcn_cvt_pk_fp8_f32(k[0],  k[1],  0, false);
    a = __builtin_amdgcn_cvt_pk_fp8_f32(k[2],  k[3],  a, true);
    r.x = (unsigned)a;
    a = __builtin_amdgcn_cvt_pk_fp8_f32(k[4],  k[5],  0, false);
    a = __builtin_amdgcn_cvt_pk_fp8_f32(k[6],  k[7],  a, true);
    r.y = (unsigned)a;
    a = __builtin_amdgcn_cvt_pk_fp8_f32(k[8],  k[9],  0, false);
    a = __builtin_amdgcn_cvt_pk_fp8_f32(k[10], k[11], a, true);
    r.z = (unsigned)a;
    a = __builtin_amdgcn_cvt_pk_fp8_f32(k[12], k[13], 0, false);
    a = __builtin_amdgcn_cvt_pk_fp8_f32(k[14], k[15], a, true);
    r.w = (unsigned)a;
    return r;
}

__device__ __forceinline__ void unpack_fp8_16(uint4 r, float* f) {
    f32x2 p;
    p = __builtin_amdgcn_cvt_pk_f32_fp8((int)r.x, false); f[0]  = p.x; f[1]  = p.y;
    p = __builtin_amdgcn_cvt_pk_f32_fp8((int)r.x, true);  f[2]  = p.x; f[3]  = p.y;
    p = __builtin_amdgcn_cvt_pk_f32_fp8((int)r.y, false); f[4]  = p.x; f[5]  = p.y;
    p = __builtin_amdgcn_cvt_pk_f32_fp8((int)r.y, true);  f[6]  = p.x; f[7]  = p.y;
    p = __builtin_amdgcn_cvt_pk_f32_fp8((int)r.z, false); f[8]  = p.x; f[9]  = p.y;
    p = __builtin_amdgcn_cvt_pk_f32_fp8((int)r.z, true);  f[10] = p.x; f[11] = p.y;
    p = __builtin_amdgcn_cvt_pk_f32_fp8((int)r.w, false); f[12] = p.x; f[13] = p.y;
    p = __builtin_amdgcn_cvt_pk_f32_fp8((int)r.w, true);  f[14] = p.x; f[15] = p.y;
}

// ---------- cached-K path ----------

// zero the 20 colsum ping-pong buffers
__global__ __launch_bounds__(THREADS) void sk_zero(float* __restrict__ csum_all) {
    const int i = blockIdx.x * THREADS + threadIdx.x;
    csum_all[i] = 0.0f;
}

// Iteration 1 fused with K16+K8 construction. v = 1 (no csum_in).
// Wave-per-row: wave w handles rows [row0 + w*16, row0 + w*16 + 16).
// Lane owns columns 16*lane .. 16*lane+15 of each row.
__global__ __launch_bounds__(THREADS) void sk_build(
        const float* __restrict__ C, const float* __restrict__ eps,
        uint4* __restrict__ K16, uint4* __restrict__ K8,
        float* __restrict__ u, float* __restrict__ csum_out) {
    __shared__ float4 smc[4][N / 4];  // 16 KB: per-wave column partials
    const int t = threadIdx.x;
    const int lane = t & 63, w = t >> 6;
    const int b = blockIdx.y;
    const int row0 = blockIdx.x * ROWS_PER_BLOCK + w * 16;
    const float nie = -1.0f / eps[0];

    const float4* __restrict__ Cp =
        (const float4*)(C + ((size_t)b * N + row0) * N) + lane * 4;
    uint4* __restrict__ Kp16 = K16 + ((size_t)b * N + row0) * NU4 + lane * 2;
    uint4* __restrict__ Kp8  = K8  + ((size_t)b * N + row0) * NU4F8 + lane;

    float colacc[16];
    #pragma unroll
    for (int q = 0; q < 16; ++q) colacc[q] = 0.0f;

    float4 cur[4];
    #pragma unroll
    for (int q = 0; q < 4; ++q) cur[q] = Cp[q];

    for (int i = 0; i < 16; ++i) {
        float4 nxt[4];
        if (i < 15) {
            #pragma unroll
            for (int q = 0; q < 4; ++q) nxt[q] = Cp[(i + 1) * (N / 4) + q];
        }
        float k[16];
        const float* cf = (const float*)cur;
        #pragma unroll
        for (int q = 0; q < 16; ++q) k[q] = __expf(cf[q] * nie);

        Kp16[(size_t)i * NU4]     = h8_pack(k);
        Kp16[(size_t)i * NU4 + 1] = h8_pack(k + 8);
        Kp8[(size_t)i * NU4F8]    = pack_fp8_16(k);

        // row sum (v = 1), balanced tree; exact fp32 k for iteration 1
        float s = (((k[0] + k[1]) + (k[2] + k[3])) + ((k[4] + k[5]) + (k[6] + k[7])))
                + (((k[8] + k[9]) + (k[10] + k[11])) + ((k[12] + k[13]) + (k[14] + k[15])));
        #pragma unroll
        for (int off = 32; off; off >>= 1) s += __shfl_xor(s, off, 64);
        const float ui = 1.0f / s;
        if (lane == 0) u[b * N + row0 + i] = ui;

        #pragma unroll
        for (int q = 0; q < 16; ++q) colacc[q] += k[q] * ui;

        if (i < 15) {
            #pragma unroll
            for (int q = 0; q < 4; ++q) cur[q] = nxt[q];
        }
    }

    #pragma unroll
    for (int q = 0; q < 4; ++q)
        smc[w][lane * 4 + q] = make_float4(colacc[4 * q], colacc[4 * q + 1],
                                           colacc[4 * q + 2], colacc[4 * q + 3]);
    __syncthreads();
    float4 s0 = smc[0][t], s1 = smc[1][t], s2 = smc[2][t], s3 = smc[3][t];
    float4 sum;
    sum.x = (s0.x + s1.x) + (s2.x + s3.x);
    sum.y = (s0.y + s1.y) + (s2.y + s3.y);
    sum.z = (s0.z + s1.z) + (s2.z + s3.z);
    sum.w = (s0.w + s1.w) + (s2.w + s3.w);
    float* cs = csum_out + b * N + 4 * t;
    atomicAdd(cs + 0, sum.x);
    atomicAdd(cs + 1, sum.y);
    atomicAdd(cs + 2, sum.z);
    atomicAdd(cs + 3, sum.w);
}

// One Sinkhorn iteration from fp8 K (iterations 2..19). No u write --
// u is only consumed by sk_final, which uses iteration 20's u.
// One fully-coalesced dwordx4 per row per wave (16 fp8/lane), depth-2
// row prefetch to cover L3 latency.
__global__ __launch_bounds__(THREADS) void sk_iter8(
        const uint4* __restrict__ K8, const float* __restrict__ csum_in,
        float* __restrict__ csum_out) {
    __shared__ float4 smc[4][N / 4];  // 16 KB
    const int t = threadIdx.x;
    const int lane = t & 63, w = t >> 6;
    const int b = blockIdx.y;
    const int row0 = blockIdx.x * ROWS_PER_BLOCK + w * 16;

    const float4* __restrict__ cin = (const float4*)(csum_in + b * N) + lane * 4;
    float vv[16];
    #pragma unroll
    for (int q = 0; q < 4; ++q) {
        float4 c = cin[q];
        vv[4 * q + 0] = 1.0f / c.x;
        vv[4 * q + 1] = 1.0f / c.y;
        vv[4 * q + 2] = 1.0f / c.z;
        vv[4 * q + 3] = 1.0f / c.w;
    }

    const uint4* __restrict__ Kp = K8 + ((size_t)b * N + row0) * NU4F8 + lane;

    float colacc[16];
    #pragma unroll
    for (int q = 0; q < 16; ++q) colacc[q] = 0.0f;

    uint4 c0 = Kp[0];
    uint4 c1 = Kp[NU4F8];
    for (int i = 0; i < 16; ++i) {
        uint4 c2;
        if (i < 14) c2 = Kp[(size_t)(i + 2) * NU4F8];

        float k[16];
        unpack_fp8_16(c0, k);

        float pa = (k[0] * vv[0] + k[1] * vv[1]) + (k[2] * vv[2] + k[3] * vv[3]);
        float pb = (k[4] * vv[4] + k[5] * vv[5]) + (k[6] * vv[6] + k[7] * vv[7]);
        float pc = (k[8] * vv[8] + k[9] * vv[9]) + (k[10] * vv[10] + k[11] * vv[11]);
        float pd = (k[12] * vv[12] + k[13] * vv[13]) + (k[14] * vv[14] + k[15] * vv[15]);
        float s = (pa + pb) + (pc + pd);

        #pragma unroll
        for (int off = 32; off; off >>= 1) s += __shfl_xor(s, off, 64);
        const float ui = 1.0f / s;

        #pragma unroll
        for (int q = 0; q < 16; ++q) colacc[q] += k[q] * ui;

        c0 = c1;
        if (i < 14) c1 = c2;
    }

    #pragma unroll
    for (int q = 0; q < 4; ++q)
        smc[w][lane * 4 + q] = make_float4(colacc[4 * q], colacc[4 * q + 1],
                                           colacc[4 * q + 2], colacc[4 * q + 3]);
    __syncthreads();
    float4 s0 = smc[0][t], s1 = smc[1][t], s2 = smc[2][t], s3 = smc[3][t];
    float4 sum;
    sum.x = (s0.x + s1.x) + (s2.x + s3.x);
    sum.y = (s0.y + s1.y) + (s2.y + s3.y);
    sum.z = (s0.z + s1.z) + (s2.z + s3.z);
    sum.w = (s0.w + s1.w) + (s2.w + s3.w);
    float* cs = csum_out + b * N + 4 * t;
    atomicAdd(cs + 0, sum.x);
    atomicAdd(cs + 1, sum.y);
    atomicAdd(cs + 2, sum.z);
    atomicAdd(cs + 3, sum.w);
}

// Iteration 20 from fp16 K (writes u for sk_final).
__global__ __launch_bounds__(THREADS) void sk_iter(
        const uint4* __restrict__ K, const float* __restrict__ csum_in,
        float* __restrict__ u, float* __restrict__ csum_out) {
    __shared__ float4 smc[4][N / 4];  // 16 KB
    const int t = threadIdx.x;
    const int lane = t & 63, w = t >> 6;
    const int b = blockIdx.y;
    const int row0 = blockIdx.x * ROWS_PER_BLOCK + w * 16;

    const float4* __restrict__ cin = (const float4*)(csum_in + b * N) + lane * 4;
    float vv[16];
    #pragma unroll
    for (int q = 0; q < 4; ++q) {
        float4 c = cin[q];
        vv[4 * q + 0] = 1.0f / c.x;
        vv[4 * q + 1] = 1.0f / c.y;
        vv[4 * q + 2] = 1.0f / c.z;
        vv[4 * q + 3] = 1.0f / c.w;
    }

    const uint4* __restrict__ Kp = K + ((size_t)b * N + row0) * NU4 + lane * 2;

    float colacc[16];
    #pragma unroll
    for (int q = 0; q < 16; ++q) colacc[q] = 0.0f;

    uint4 c0 = Kp[0], c1 = Kp[1];
    for (int i = 0; i < 16; ++i) {
        uint4 n0, n1;
        if (i < 15) {
            n0 = Kp[(size_t)(i + 1) * NU4];
            n1 = Kp[(size_t)(i + 1) * NU4 + 1];
        }
        float k[16];
        h8_unpack(c0, k);
        h8_unpack(c1, k + 8);

        float pa = (k[0] * vv[0] + k[1] * vv[1]) + (k[2] * vv[2] + k[3] * vv[3]);
        float pb = (k[4] * vv[4] + k[5] * vv[5]) + (k[6] * vv[6] + k[7] * vv[7]);
        float pc = (k[8] * vv[8] + k[9] * vv[9]) + (k[10] * vv[10] + k[11] * vv[11]);
        float pd = (k[12] * vv[12] + k[13] * vv[13]) + (k[14] * vv[14] + k[15] * vv[15]);
        float s = (pa + pb) + (pc + pd);

        #pragma unroll
        for (int off = 32; off; off >>= 1) s += __shfl_xor(s, off, 64);
        const float ui = 1.0f / s;
        if (lane == 0) u[b * N + row0 + i] = ui;

        #pragma unroll
        for (int q = 0; q < 16; ++q) colacc[q] += k[q] * ui;

        if (i < 15) { c0 = n0; c1 = n1; }
    }

    #pragma unroll
    for (int q = 0; q < 4; ++q)
        smc[w][lane * 4 + q] = make_float4(colacc[4 * q], colacc[4 * q + 1],
                                           colacc[4 * q + 2], colacc[4 * q + 3]);
    __syncthreads();
    float4 s0 = smc[0][t], s1 = smc[1][t], s2 = smc[2][t], s3 = smc[3][t];
    float4 sum;
    sum.x = (s0.x + s1.x) + (s2.x + s3.x);
    sum.y = (s0.y + s1.y) + (s2.y + s3.y);
    sum.z = (s0.z + s1.z) + (s2.z + s3.z);
    sum.w = (s0.w + s1.w) + (s2.w + s3.w);
    float* cs = csum_out + b * N + 4 * t;
    atomicAdd(cs + 0, sum.x);
    atomicAdd(cs + 1, sum.y);
    atomicAdd(cs + 2, sum.z);
    atomicAdd(cs + 3, sum.w);
}

__global__ __launch_bounds__(THREADS) void sk_final(
        const uint2* __restrict__ K, const float* __restrict__ u,
        const float* __restrict__ csum_last, float* __restrict__ out) {
    const int t = threadIdx.x;
    const int row = blockIdx.x;
    const int b = blockIdx.y;
    const float ui = u[b * N + row];
    const float4 ci = ((const float4*)(csum_last + b * N))[t];
    const float4 vv = make_float4(1.0f / ci.x, 1.0f / ci.y, 1.0f / ci.z, 1.0f / ci.w);
    const size_t base = (size_t)b * N + row;
    float4 k = h4_to_f4((K + base * NU2)[t]);
    float4 o;
    o.x = k.x * ui * vv.x;
    o.y = k.y * ui * vv.y;
    o.z = k.z * ui * vv.z;
    o.w = k.w * ui * vv.w;
    ((float4*)(out + base * N))[t] = o;
}

// ---------- fallback all-fp32 path (round-1, known-good) ----------

__device__ __forceinline__ float block_reduce_broadcast(float val, float* lds) {
    #pragma unroll
    for (int off = 32; off > 0; off >>= 1)
        val += __shfl_xor(val, off, 64);
    const int lane = threadIdx.x & 63;
    const int wid  = threadIdx.x >> 6;
    if (lane == 0) lds[wid] = val;
    __syncthreads();
    float total = lds[0] + lds[1] + lds[2] + lds[3];
    __syncthreads();
    return total;
}

__global__ __launch_bounds__(THREADS) void sink_init(float* __restrict__ v,
                                                     float* __restrict__ colsum) {
    const int i = blockIdx.x * THREADS + threadIdx.x;
    v[i] = 1.0f;
    colsum[i] = 0.0f;
}

__global__ __launch_bounds__(THREADS) void sink_iter(
        const float* __restrict__ C, const float* __restrict__ eps,
        const float* __restrict__ v, float* __restrict__ u,
        float* __restrict__ colsum) {
    __shared__ float lds[4];
    const int t = threadIdx.x;
    const int b = blockIdx.y;
    const int row0 = blockIdx.x * ROWS_PER_BLOCK;
    const float neg_inv_eps = -1.0f / eps[0];

    const float4 vv = ((const float4*)(v + b * N))[t];
    const float4* __restrict__ Cp = (const float4*)(C + ((size_t)b * N + row0) * N);

    float4 colacc = make_float4(0.f, 0.f, 0.f, 0.f);
    float4 cur = Cp[t];
    for (int i = 0; i < ROWS_PER_BLOCK; ++i) {
        float4 nxt = cur;
        if (i + 1 < ROWS_PER_BLOCK)
            nxt = Cp[(size_t)(i + 1) * (N / 4) + t];

        float4 k;
        k.x = __expf(cur.x * neg_inv_eps);
        k.y = __expf(cur.y * neg_inv_eps);
        k.z = __expf(cur.z * neg_inv_eps);
        k.w = __expf(cur.w * neg_inv_eps);

        float s = k.x * vv.x + k.y * vv.y + k.z * vv.z + k.w * vv.w;
        float S = block_reduce_broadcast(s, lds);
        float ui = 1.0f / S;
        if (t == 0) u[b * N + row0 + i] = ui;

        colacc.x += k.x * ui;
        colacc.y += k.y * ui;
        colacc.z += k.z * ui;
        colacc.w += k.w * ui;
        cur = nxt;
    }

    float* cs = colsum + b * N + 4 * t;
    atomicAdd(cs + 0, colacc.x);
    atomicAdd(cs + 1, colacc.y);
    atomicAdd(cs + 2, colacc.z);
    atomicAdd(cs + 3, colacc.w);
}

__global__ __launch_bounds__(THREADS) void sink_fix(float* __restrict__ v,
                                                    float* __restrict__ colsum) {
    const int i = blockIdx.x * THREADS + threadIdx.x;
    v[i] = 1.0f / colsum[i];
    colsum[i] = 0.0f;
}

__global__ __launch_bounds__(THREADS) void sink_final(
        const float* __restrict__ C, const float* __restrict__ eps,
        const float* __restrict__ u, const float* __restrict__ v,
        float* __restrict__ out) {
    const int t = threadIdx.x;
    const int row = blockIdx.x;
    const int b = blockIdx.y;
    const float neg_inv_eps = -1.0f / eps[0];
    const float ui = u[b * N + row];
    const float4 vv = ((const float4*)(v + b * N))[t];
    const size_t base = ((size_t)b * N + row) * N;
    float4 c = ((const float4*)(C + base))[t];
    float4 o;
    o.x = __expf(c.x * neg_inv_eps) * ui * vv.x;
    o.y = __expf(c.y * neg_inv_eps) * ui * vv.y;
    o.z = __expf(c.z * neg_inv_eps) * ui * vv.z;
    o.w = __expf(c.w * neg_inv_eps) * ui * vv.w;
    ((float4*)(out + base))[t] = o;
}

// ---------- launch ----------

extern "C" void kernel_launch(void* const* d_in, const int* in_sizes, int n_in,
                              void* d_out, int out_size, void* d_ws, size_t ws_size,
                              hipStream_t stream) {
    const float* C   = (const float*)d_in[0];
    const float* eps = (const float*)d_in[1];
    float* out = (float*)d_out;

    const size_t k16_bytes = (size_t)BATCH * N * N * 2;   // 134 MB
    const size_t k8_bytes  = (size_t)BATCH * N * N;       // 67 MB
    const size_t uv_elems  = (size_t)BATCH * N;           // 64K floats
    const size_t needed    = k16_bytes + k8_bytes + uv_elems * 4 * (1 + NITERS);

    if (ws_size >= needed) {
        uint4* K16 = (uint4*)d_ws;
        uint4* K8  = (uint4*)((char*)d_ws + k16_bytes);
        float* u   = (float*)((char*)d_ws + k16_bytes + k8_bytes);
        float* csum = u + uv_elems;  // 20 buffers of 64K floats, csum[t-1] for iter t

        // zero all 20 colsum buffers (ws is poisoned 0xAA before every call)
        sk_zero<<<dim3(NITERS * uv_elems / THREADS), dim3(THREADS), 0, stream>>>(csum);
        // iteration 1 fused with K build (v = 1)
        sk_build<<<dim3(BLOCKS_PER_BATCH, BATCH), dim3(THREADS), 0, stream>>>(
            C, eps, K16, K8, u, csum);
        // iterations 2..19 from fp8 K
        for (int it = 2; it <= NITERS - 1; ++it) {
            sk_iter8<<<dim3(BLOCKS_PER_BATCH, BATCH), dim3(THREADS), 0, stream>>>(
                K8, csum + (size_t)(it - 2) * uv_elems,
                csum + (size_t)(it - 1) * uv_elems);
        }
        // iteration 20 from fp16 K (writes u)
        sk_iter<<<dim3(BLOCKS_PER_BATCH, BATCH), dim3(THREADS), 0, stream>>>(
            K16, csum + (size_t)(NITERS - 2) * uv_elems, u,
            csum + (size_t)(NITERS - 1) * uv_elems);
        sk_final<<<dim3(N, BATCH), dim3(THREADS), 0, stream>>>(
            (const uint2*)K16, u, csum + (size_t)(NITERS - 1) * uv_elems, out);
    } else {
        // fallback: all-fp32 path
        float* u      = (float*)d_ws;
        float* v      = u + uv_elems;
        float* colsum = v + uv_elems;
        sink_init<<<dim3(BATCH * N / THREADS), dim3(THREADS), 0, stream>>>(v, colsum);
        for (int it = 0; it < NITERS; ++it) {
            sink_iter<<<dim3(BLOCKS_PER_BATCH, BATCH), dim3(THREADS), 0, stream>>>(
                C, eps, v, u, colsum);
            sink_fix<<<dim3(BATCH * N / THREADS), dim3(THREADS), 0, stream>>>(v, colsum);
        }
        sink_final<<<dim3(N, BATCH), dim3(THREADS), 0, stream>>>(C, eps, u, v, out);
    }
}

// Round 3
// 1002.170 us; speedup vs baseline: 1.1124x; 1.0039x over previous
//
#include <hip/hip_runtime.h>
#include <hip/hip_fp16.h>

// Sinkhorn, 64 x 1024 x 1024 fp32, 20 iterations.
//
// K = exp(-C/eps); u = 1/(K v); v = 1/(K^T u); out = u_i K_ij v_j.
//
// Round-2 evidence: per-iteration time (~44 us) is invariant under 2x byte
// reduction (fp16->fp8) AND under reduction restructuring => dominated by
// per-dispatch overhead (drain/tail/launch/ramp of 20 serialized dispatches)
// plus contended csum atomics. This round fuses build + 19 iterations +
// final into ONE persistent kernel with a hand-rolled grid barrier:
//   grid = 1024 blocks (4/CU x 256 CU co-resident, __launch_bounds__(256,4)),
//   hierarchical barrier: 64 group counters -> master -> generation word.
// Block (b,bx) owns rows [bx*64, bx*64+64) of batch b in every phase, so
// K16/K8 never cross XCDs (same block writes then reads them). Only csum
// crosses blocks: device-scope atomicAdd + __threadfence in the barrier.
// u lives in LDS (no global u). Final phase uses the coalesced
// thread-per-float4 layout. csum atomics staggered by 64*bx columns to
// decorrelate same-address contention.
// Falls back to the round-2 multi-kernel path if occupancy check fails,
// and to the all-fp32 path if ws is too small.

#define BATCH 64
#define N 1024
#define NITERS 20
#define RPB 64                   // rows per block
#define BPB 16                   // blocks per batch
#define NBLK (BATCH * BPB)       // 1024 blocks
#define THREADS 256
#define NU2 (N / 4)              // uint2 (4 halves) per fp16 row
#define NU4 (N / 8)              // uint4 (8 halves) per fp16 row
#define NU4F8 (N / 16)           // uint4 (16 fp8) per fp8 row
#define NGRP 64                  // barrier groups
#define CSUM_ELEMS ((size_t)NITERS * BATCH * N)
#define BAR_WORDS 128            // grp[64], master, gen, padding

typedef float f32x2 __attribute__((ext_vector_type(2)));

// ---------- fp16 pack/unpack helpers ----------
union H2U { __half2 h; unsigned u; };

__device__ __forceinline__ float4 h4_to_f4(uint2 r) {
    H2U a, b;
    a.u = r.x; b.u = r.y;
    float2 fa = __half22float2(a.h);
    float2 fb = __half22float2(b.h);
    return make_float4(fa.x, fa.y, fb.x, fb.y);
}

__device__ __forceinline__ void h8_unpack(uint4 r, float* f) {
    H2U a, b, c, d;
    a.u = r.x; b.u = r.y; c.u = r.z; d.u = r.w;
    float2 fa = __half22float2(a.h), fb = __half22float2(b.h);
    float2 fc = __half22float2(c.h), fd = __half22float2(d.h);
    f[0] = fa.x; f[1] = fa.y; f[2] = fb.x; f[3] = fb.y;
    f[4] = fc.x; f[5] = fc.y; f[6] = fd.x; f[7] = fd.y;
}

__device__ __forceinline__ uint4 h8_pack(const float* f) {
    H2U a, b, c, d;
    a.h = __float22half2_rn(make_float2(f[0], f[1]));
    b.h = __float22half2_rn(make_float2(f[2], f[3]));
    c.h = __float22half2_rn(make_float2(f[4], f[5]));
    d.h = __float22half2_rn(make_float2(f[6], f[7]));
    uint4 r; r.x = a.u; r.y = b.u; r.z = c.u; r.w = d.u;
    return r;
}

// ---------- fp8 (OCP e4m3) pack/unpack via gfx950 HW cvt ----------
__device__ __forceinline__ uint4 pack_fp8_16(const float* k) {
    uint4 r;
    int a;
    a = __builtin_amdgcn_cvt_pk_fp8_f32(k[0],  k[1],  0, false);
    a = __builtin_amdgcn_cvt_pk_fp8_f32(k[2],  k[3],  a, true);
    r.x = (unsigned)a;
    a = __builtin_amdgcn_cvt_pk_fp8_f32(k[4],  k[5],  0, false);
    a = __builtin_amdgcn_cvt_pk_fp8_f32(k[6],  k[7],  a, true);
    r.y = (unsigned)a;
    a = __builtin_amdgcn_cvt_pk_fp8_f32(k[8],  k[9],  0, false);
    a = __builtin_amdgcn_cvt_pk_fp8_f32(k[10], k[11], a, true);
    r.z = (unsigned)a;
    a = __builtin_amdgcn_cvt_pk_fp8_f32(k[12], k[13], 0, false);
    a = __builtin_amdgcn_cvt_pk_fp8_f32(k[14], k[15], a, true);
    r.w = (unsigned)a;
    return r;
}

__device__ __forceinline__ void unpack_fp8_16(uint4 r, float* f) {
    f32x2 p;
    p = __builtin_amdgcn_cvt_pk_f32_fp8((int)r.x, false); f[0]  = p.x; f[1]  = p.y;
    p = __builtin_amdgcn_cvt_pk_f32_fp8((int)r.x, true);  f[2]  = p.x; f[3]  = p.y;
    p = __builtin_amdgcn_cvt_pk_f32_fp8((int)r.y, false); f[4]  = p.x; f[5]  = p.y;
    p = __builtin_amdgcn_cvt_pk_f32_fp8((int)r.y, true);  f[6]  = p.x; f[7]  = p.y;
    p = __builtin_amdgcn_cvt_pk_f32_fp8((int)r.z, false); f[8]  = p.x; f[9]  = p.y;
    p = __builtin_amdgcn_cvt_pk_f32_fp8((int)r.z, true);  f[10] = p.x; f[11] = p.y;
    p = __builtin_amdgcn_cvt_pk_f32_fp8((int)r.w, false); f[12] = p.x; f[13] = p.y;
    p = __builtin_amdgcn_cvt_pk_f32_fp8((int)r.w, true);  f[14] = p.x; f[15] = p.y;
}

// ---------- zero csum + barrier words ----------
__global__ __launch_bounds__(THREADS) void sk_zero(float* __restrict__ csum_all,
                                                   int total) {
    const int i = blockIdx.x * THREADS + threadIdx.x;
    if (i < total) csum_all[i] = 0.0f;
}

// ---------- hierarchical grid barrier ----------
// bar layout: grp[NGRP], master at [NGRP], gen at [NGRP+1]. All zeroed.
__device__ __forceinline__ void gbar(unsigned* __restrict__ bar,
                                     unsigned& gencount) {
    __syncthreads();  // drains all threads' vmem (atomics) before arrival
    if (threadIdx.x == 0) {
        __threadfence();  // release: prior writes device-visible
        unsigned* grp    = bar;
        unsigned* master = bar + NGRP;
        unsigned* gen    = bar + NGRP + 1;
        const unsigned gid = blockIdx.x & (NGRP - 1);
        if (atomicAdd(&grp[gid], 1u) == (NBLK / NGRP) - 1u) {
            if (atomicAdd(master, 1u) == NGRP - 1u) {
                // last arriver: reset counters, then release generation
                #pragma unroll
                for (int i = 0; i < NGRP; ++i) atomicExch(&grp[i], 0u);
                atomicExch(master, 0u);
                __threadfence();
                atomicAdd(gen, 1u);
            }
        }
        while (__hip_atomic_load(gen, __ATOMIC_RELAXED,
                                 __HIP_MEMORY_SCOPE_AGENT) == gencount)
            __builtin_amdgcn_s_sleep(2);
        __threadfence();  // acquire: see other blocks' csum writes
    }
    __syncthreads();
    ++gencount;
}

// ---------- the fused persistent kernel ----------
__global__ __launch_bounds__(THREADS, 4) void sk_fused(
        const float* __restrict__ C, const float* __restrict__ eps,
        uint4* __restrict__ K16, uint4* __restrict__ K8,
        float* __restrict__ csum, unsigned* __restrict__ bar,
        float* __restrict__ out) {
    __shared__ float4 smc[4][N / 4];  // 16 KB column-partial combine
    __shared__ float u_lds[RPB];
    const int t = threadIdx.x;
    const int lane = t & 63, w = t >> 6;
    const int bid = blockIdx.x;
    const int b = bid >> 4, bx = bid & 15;
    const int row0 = bx * RPB + w * 16;
    const int tt = (t + 16 * bx) & 255;  // staggered column group
    unsigned gencount = 0;

    // ---- Phase 0: build K16 + K8, iteration 1 (v = 1) ----
    {
        const float nie = -1.0f / eps[0];
        const float4* __restrict__ Cp =
            (const float4*)(C + ((size_t)b * N + row0) * N) + lane * 4;
        uint4* __restrict__ Kp16 = K16 + ((size_t)b * N + row0) * NU4 + lane * 2;
        uint4* __restrict__ Kp8  = K8  + ((size_t)b * N + row0) * NU4F8 + lane;

        float colacc[16];
        #pragma unroll
        for (int q = 0; q < 16; ++q) colacc[q] = 0.0f;

        float4 cur[4];
        #pragma unroll
        for (int q = 0; q < 4; ++q) cur[q] = Cp[q];

        #pragma unroll
        for (int i = 0; i < 16; ++i) {
            float4 nxt[4];
            if (i < 15) {
                #pragma unroll
                for (int q = 0; q < 4; ++q) nxt[q] = Cp[(i + 1) * (N / 4) + q];
            }
            float k[16];
            const float* cf = (const float*)cur;
            #pragma unroll
            for (int q = 0; q < 16; ++q) k[q] = __expf(cf[q] * nie);

            Kp16[(size_t)i * NU4]     = h8_pack(k);
            Kp16[(size_t)i * NU4 + 1] = h8_pack(k + 8);
            Kp8[(size_t)i * NU4F8]    = pack_fp8_16(k);

            float s = (((k[0] + k[1]) + (k[2] + k[3])) + ((k[4] + k[5]) + (k[6] + k[7])))
                    + (((k[8] + k[9]) + (k[10] + k[11])) + ((k[12] + k[13]) + (k[14] + k[15])));
            #pragma unroll
            for (int off = 32; off; off >>= 1) s += __shfl_xor(s, off, 64);
            const float ui = 1.0f / s;

            #pragma unroll
            for (int q = 0; q < 16; ++q) colacc[q] += k[q] * ui;

            if (i < 15) {
                #pragma unroll
                for (int q = 0; q < 4; ++q) cur[q] = nxt[q];
            }
        }

        #pragma unroll
        for (int q = 0; q < 4; ++q)
            smc[w][lane * 4 + q] = make_float4(colacc[4 * q], colacc[4 * q + 1],
                                               colacc[4 * q + 2], colacc[4 * q + 3]);
        __syncthreads();
        float4 s0 = smc[0][tt], s1 = smc[1][tt], s2 = smc[2][tt], s3 = smc[3][tt];
        float* cs = csum + b * N + 4 * tt;
        atomicAdd(cs + 0, (s0.x + s1.x) + (s2.x + s3.x));
        atomicAdd(cs + 1, (s0.y + s1.y) + (s2.y + s3.y));
        atomicAdd(cs + 2, (s0.z + s1.z) + (s2.z + s3.z));
        atomicAdd(cs + 3, (s0.w + s1.w) + (s2.w + s3.w));
    }
    gbar(bar, gencount);

    // ---- Phases 1..18: fp8 iterations (overall iterations 2..19) ----
    const uint4* __restrict__ Kp8r = K8 + ((size_t)b * N + row0) * NU4F8 + lane;
    #pragma unroll 1
    for (int p = 1; p <= 18; ++p) {
        const float4* __restrict__ cin =
            (const float4*)(csum + (size_t)(p - 1) * BATCH * N + b * N) + lane * 4;
        float vv[16];
        #pragma unroll
        for (int q = 0; q < 4; ++q) {
            float4 c = cin[q];
            vv[4 * q + 0] = 1.0f / c.x;
            vv[4 * q + 1] = 1.0f / c.y;
            vv[4 * q + 2] = 1.0f / c.z;
            vv[4 * q + 3] = 1.0f / c.w;
        }

        float colacc[16];
        #pragma unroll
        for (int q = 0; q < 16; ++q) colacc[q] = 0.0f;

        uint4 buf[4];
        #pragma unroll
        for (int q = 0; q < 4; ++q) buf[q] = Kp8r[(size_t)q * NU4F8];

        __syncthreads();  // protect smc from previous phase's tail readers
        #pragma unroll
        for (int i = 0; i < 16; ++i) {
            uint4 nx;
            if (i < 12) nx = Kp8r[(size_t)(i + 4) * NU4F8];

            float k[16];
            unpack_fp8_16(buf[i & 3], k);

            float pa = (k[0] * vv[0] + k[1] * vv[1]) + (k[2] * vv[2] + k[3] * vv[3]);
            float pb = (k[4] * vv[4] + k[5] * vv[5]) + (k[6] * vv[6] + k[7] * vv[7]);
            float pc = (k[8] * vv[8] + k[9] * vv[9]) + (k[10] * vv[10] + k[11] * vv[11]);
            float pd = (k[12] * vv[12] + k[13] * vv[13]) + (k[14] * vv[14] + k[15] * vv[15]);
            float s = (pa + pb) + (pc + pd);

            #pragma unroll
            for (int off = 32; off; off >>= 1) s += __shfl_xor(s, off, 64);
            const float ui = 1.0f / s;

            #pragma unroll
            for (int q = 0; q < 16; ++q) colacc[q] += k[q] * ui;

            if (i < 12) buf[i & 3] = nx;
        }

        #pragma unroll
        for (int q = 0; q < 4; ++q)
            smc[w][lane * 4 + q] = make_float4(colacc[4 * q], colacc[4 * q + 1],
                                               colacc[4 * q + 2], colacc[4 * q + 3]);
        __syncthreads();
        float4 s0 = smc[0][tt], s1 = smc[1][tt], s2 = smc[2][tt], s3 = smc[3][tt];
        float* cs = csum + (size_t)p * BATCH * N + b * N + 4 * tt;
        atomicAdd(cs + 0, (s0.x + s1.x) + (s2.x + s3.x));
        atomicAdd(cs + 1, (s0.y + s1.y) + (s2.y + s3.y));
        atomicAdd(cs + 2, (s0.z + s1.z) + (s2.z + s3.z));
        atomicAdd(cs + 3, (s0.w + s1.w) + (s2.w + s3.w));
        gbar(bar, gencount);
    }

    // ---- Phase 19: fp16 iteration 20 (u kept in LDS) ----
    {
        const float4* __restrict__ cin =
            (const float4*)(csum + (size_t)18 * BATCH * N + b * N) + lane * 4;
        float vv[16];
        #pragma unroll
        for (int q = 0; q < 4; ++q) {
            float4 c = cin[q];
            vv[4 * q + 0] = 1.0f / c.x;
            vv[4 * q + 1] = 1.0f / c.y;
            vv[4 * q + 2] = 1.0f / c.z;
            vv[4 * q + 3] = 1.0f / c.w;
        }

        const uint4* __restrict__ Kp = K16 + ((size_t)b * N + row0) * NU4 + lane * 2;

        float colacc[16];
        #pragma unroll
        for (int q = 0; q < 16; ++q) colacc[q] = 0.0f;

        uint4 c0 = Kp[0], c1 = Kp[1];
        #pragma unroll
        for (int i = 0; i < 16; ++i) {
            uint4 n0, n1;
            if (i < 15) {
                n0 = Kp[(size_t)(i + 1) * NU4];
                n1 = Kp[(size_t)(i + 1) * NU4 + 1];
            }
            float k[16];
            h8_unpack(c0, k);
            h8_unpack(c1, k + 8);

            float pa = (k[0] * vv[0] + k[1] * vv[1]) + (k[2] * vv[2] + k[3] * vv[3]);
            float pb = (k[4] * vv[4] + k[5] * vv[5]) + (k[6] * vv[6] + k[7] * vv[7]);
            float pc = (k[8] * vv[8] + k[9] * vv[9]) + (k[10] * vv[10] + k[11] * vv[11]);
            float pd = (k[12] * vv[12] + k[13] * vv[13]) + (k[14] * vv[14] + k[15] * vv[15]);
            float s = (pa + pb) + (pc + pd);

            #pragma unroll
            for (int off = 32; off; off >>= 1) s += __shfl_xor(s, off, 64);
            const float ui = 1.0f / s;
            if (lane == 0) u_lds[w * 16 + i] = ui;

            #pragma unroll
            for (int q = 0; q < 16; ++q) colacc[q] += k[q] * ui;

            if (i < 15) { c0 = n0; c1 = n1; }
        }

        #pragma unroll
        for (int q = 0; q < 4; ++q)
            smc[w][lane * 4 + q] = make_float4(colacc[4 * q], colacc[4 * q + 1],
                                               colacc[4 * q + 2], colacc[4 * q + 3]);
        __syncthreads();
        float4 s0 = smc[0][tt], s1 = smc[1][tt], s2 = smc[2][tt], s3 = smc[3][tt];
        float* cs = csum + (size_t)19 * BATCH * N + b * N + 4 * tt;
        atomicAdd(cs + 0, (s0.x + s1.x) + (s2.x + s3.x));
        atomicAdd(cs + 1, (s0.y + s1.y) + (s2.y + s3.y));
        atomicAdd(cs + 2, (s0.z + s1.z) + (s2.z + s3.z));
        atomicAdd(cs + 3, (s0.w + s1.w) + (s2.w + s3.w));
    }
    gbar(bar, gencount);

    // ---- Phase 20: final product, coalesced thread-per-float4 ----
    {
        const float4 ci = ((const float4*)(csum + (size_t)19 * BATCH * N + b * N))[t];
        const float4 vv = make_float4(1.0f / ci.x, 1.0f / ci.y,
                                      1.0f / ci.z, 1.0f / ci.w);
        const size_t rowbase = (size_t)b * N + (size_t)bx * RPB;
        const uint2* __restrict__ K2 = (const uint2*)K16;

        uint2 kc = K2[rowbase * NU2 + t];
        for (int r = 0; r < RPB; ++r) {
            uint2 kn;
            if (r < RPB - 1) kn = K2[(rowbase + r + 1) * NU2 + t];
            const float ur = u_lds[r];
            float4 k = h4_to_f4(kc);
            float4 o;
            o.x = k.x * ur * vv.x;
            o.y = k.y * ur * vv.y;
            o.z = k.z * ur * vv.z;
            o.w = k.w * ur * vv.w;
            ((float4*)(out + (rowbase + r) * N))[t] = o;
            kc = kn;
        }
    }
}

// ---------- round-2 multi-kernel fallback (known-good) ----------

__global__ __launch_bounds__(THREADS) void sk_build(
        const float* __restrict__ C, const float* __restrict__ eps,
        uint4* __restrict__ K16, uint4* __restrict__ K8,
        float* __restrict__ u, float* __restrict__ csum_out) {
    __shared__ float4 smc[4][N / 4];
    const int t = threadIdx.x;
    const int lane = t & 63, w = t >> 6;
    const int b = blockIdx.y;
    const int row0 = blockIdx.x * RPB + w * 16;
    const float nie = -1.0f / eps[0];

    const float4* __restrict__ Cp =
        (const float4*)(C + ((size_t)b * N + row0) * N) + lane * 4;
    uint4* __restrict__ Kp16 = K16 + ((size_t)b * N + row0) * NU4 + lane * 2;
    uint4* __restrict__ Kp8  = K8  + ((size_t)b * N + row0) * NU4F8 + lane;

    float colacc[16];
    #pragma unroll
    for (int q = 0; q < 16; ++q) colacc[q] = 0.0f;

    float4 cur[4];
    #pragma unroll
    for (int q = 0; q < 4; ++q) cur[q] = Cp[q];

    for (int i = 0; i < 16; ++i) {
        float4 nxt[4];
        if (i < 15) {
            #pragma unroll
            for (int q = 0; q < 4; ++q) nxt[q] = Cp[(i + 1) * (N / 4) + q];
        }
        float k[16];
        const float* cf = (const float*)cur;
        #pragma unroll
        for (int q = 0; q < 16; ++q) k[q] = __expf(cf[q] * nie);

        Kp16[(size_t)i * NU4]     = h8_pack(k);
        Kp16[(size_t)i * NU4 + 1] = h8_pack(k + 8);
        Kp8[(size_t)i * NU4F8]    = pack_fp8_16(k);

        float s = (((k[0] + k[1]) + (k[2] + k[3])) + ((k[4] + k[5]) + (k[6] + k[7])))
                + (((k[8] + k[9]) + (k[10] + k[11])) + ((k[12] + k[13]) + (k[14] + k[15])));
        #pragma unroll
        for (int off = 32; off; off >>= 1) s += __shfl_xor(s, off, 64);
        const float ui = 1.0f / s;
        if (lane == 0) u[b * N + row0 + i] = ui;

        #pragma unroll
        for (int q = 0; q < 16; ++q) colacc[q] += k[q] * ui;

        if (i < 15) {
            #pragma unroll
            for (int q = 0; q < 4; ++q) cur[q] = nxt[q];
        }
    }

    #pragma unroll
    for (int q = 0; q < 4; ++q)
        smc[w][lane * 4 + q] = make_float4(colacc[4 * q], colacc[4 * q + 1],
                                           colacc[4 * q + 2], colacc[4 * q + 3]);
    __syncthreads();
    float4 s0 = smc[0][t], s1 = smc[1][t], s2 = smc[2][t], s3 = smc[3][t];
    float* cs = csum_out + b * N + 4 * t;
    atomicAdd(cs + 0, (s0.x + s1.x) + (s2.x + s3.x));
    atomicAdd(cs + 1, (s0.y + s1.y) + (s2.y + s3.y));
    atomicAdd(cs + 2, (s0.z + s1.z) + (s2.z + s3.z));
    atomicAdd(cs + 3, (s0.w + s1.w) + (s2.w + s3.w));
}

__global__ __launch_bounds__(THREADS) void sk_iter8(
        const uint4* __restrict__ K8, const float* __restrict__ csum_in,
        float* __restrict__ csum_out) {
    __shared__ float4 smc[4][N / 4];
    const int t = threadIdx.x;
    const int lane = t & 63, w = t >> 6;
    const int b = blockIdx.y;
    const int row0 = blockIdx.x * RPB + w * 16;

    const float4* __restrict__ cin = (const float4*)(csum_in + b * N) + lane * 4;
    float vv[16];
    #pragma unroll
    for (int q = 0; q < 4; ++q) {
        float4 c = cin[q];
        vv[4 * q + 0] = 1.0f / c.x;
        vv[4 * q + 1] = 1.0f / c.y;
        vv[4 * q + 2] = 1.0f / c.z;
        vv[4 * q + 3] = 1.0f / c.w;
    }

    const uint4* __restrict__ Kp = K8 + ((size_t)b * N + row0) * NU4F8 + lane;

    float colacc[16];
    #pragma unroll
    for (int q = 0; q < 16; ++q) colacc[q] = 0.0f;

    uint4 c0 = Kp[0];
    uint4 c1 = Kp[NU4F8];
    for (int i = 0; i < 16; ++i) {
        uint4 c2;
        if (i < 14) c2 = Kp[(size_t)(i + 2) * NU4F8];

        float k[16];
        unpack_fp8_16(c0, k);

        float pa = (k[0] * vv[0] + k[1] * vv[1]) + (k[2] * vv[2] + k[3] * vv[3]);
        float pb = (k[4] * vv[4] + k[5] * vv[5]) + (k[6] * vv[6] + k[7] * vv[7]);
        float pc = (k[8] * vv[8] + k[9] * vv[9]) + (k[10] * vv[10] + k[11] * vv[11]);
        float pd = (k[12] * vv[12] + k[13] * vv[13]) + (k[14] * vv[14] + k[15] * vv[15]);
        float s = (pa + pb) + (pc + pd);

        #pragma unroll
        for (int off = 32; off; off >>= 1) s += __shfl_xor(s, off, 64);
        const float ui = 1.0f / s;

        #pragma unroll
        for (int q = 0; q < 16; ++q) colacc[q] += k[q] * ui;

        c0 = c1;
        if (i < 14) c1 = c2;
    }

    #pragma unroll
    for (int q = 0; q < 4; ++q)
        smc[w][lane * 4 + q] = make_float4(colacc[4 * q], colacc[4 * q + 1],
                                           colacc[4 * q + 2], colacc[4 * q + 3]);
    __syncthreads();
    float4 s0 = smc[0][t], s1 = smc[1][t], s2 = smc[2][t], s3 = smc[3][t];
    float* cs = csum_out + b * N + 4 * t;
    atomicAdd(cs + 0, (s0.x + s1.x) + (s2.x + s3.x));
    atomicAdd(cs + 1, (s0.y + s1.y) + (s2.y + s3.y));
    atomicAdd(cs + 2, (s0.z + s1.z) + (s2.z + s3.z));
    atomicAdd(cs + 3, (s0.w + s1.w) + (s2.w + s3.w));
}

__global__ __launch_bounds__(THREADS) void sk_iter(
        const uint4* __restrict__ K, const float* __restrict__ csum_in,
        float* __restrict__ u, float* __restrict__ csum_out) {
    __shared__ float4 smc[4][N / 4];
    const int t = threadIdx.x;
    const int lane = t & 63, w = t >> 6;
    const int b = blockIdx.y;
    const int row0 = blockIdx.x * RPB + w * 16;

    const float4* __restrict__ cin = (const float4*)(csum_in + b * N) + lane * 4;
    float vv[16];
    #pragma unroll
    for (int q = 0; q < 4; ++q) {
        float4 c = cin[q];
        vv[4 * q + 0] = 1.0f / c.x;
        vv[4 * q + 1] = 1.0f / c.y;
        vv[4 * q + 2] = 1.0f / c.z;
        vv[4 * q + 3] = 1.0f / c.w;
    }

    const uint4* __restrict__ Kp = K + ((size_t)b * N + row0) * NU4 + lane * 2;

    float colacc[16];
    #pragma unroll
    for (int q = 0; q < 16; ++q) colacc[q] = 0.0f;

    uint4 c0 = Kp[0], c1 = Kp[1];
    for (int i = 0; i < 16; ++i) {
        uint4 n0, n1;
        if (i < 15) {
            n0 = Kp[(size_t)(i + 1) * NU4];
            n1 = Kp[(size_t)(i + 1) * NU4 + 1];
        }
        float k[16];
        h8_unpack(c0, k);
        h8_unpack(c1, k + 8);

        float pa = (k[0] * vv[0] + k[1] * vv[1]) + (k[2] * vv[2] + k[3] * vv[3]);
        float pb = (k[4] * vv[4] + k[5] * vv[5]) + (k[6] * vv[6] + k[7] * vv[7]);
        float pc = (k[8] * vv[8] + k[9] * vv[9]) + (k[10] * vv[10] + k[11] * vv[11]);
        float pd = (k[12] * vv[12] + k[13] * vv[13]) + (k[14] * vv[14] + k[15] * vv[15]);
        float s = (pa + pb) + (pc + pd);

        #pragma unroll
        for (int off = 32; off; off >>= 1) s += __shfl_xor(s, off, 64);
        const float ui = 1.0f / s;
        if (lane == 0) u[b * N + row0 + i] = ui;

        #pragma unroll
        for (int q = 0; q < 16; ++q) colacc[q] += k[q] * ui;

        if (i < 15) { c0 = n0; c1 = n1; }
    }

    #pragma unroll
    for (int q = 0; q < 4; ++q)
        smc[w][lane * 4 + q] = make_float4(colacc[4 * q], colacc[4 * q + 1],
                                           colacc[4 * q + 2], colacc[4 * q + 3]);
    __syncthreads();
    float4 s0 = smc[0][t], s1 = smc[1][t], s2 = smc[2][t], s3 = smc[3][t];
    float* cs = csum_out + b * N + 4 * t;
    atomicAdd(cs + 0, (s0.x + s1.x) + (s2.x + s3.x));
    atomicAdd(cs + 1, (s0.y + s1.y) + (s2.y + s3.y));
    atomicAdd(cs + 2, (s0.z + s1.z) + (s2.z + s3.z));
    atomicAdd(cs + 3, (s0.w + s1.w) + (s2.w + s3.w));
}

__global__ __launch_bounds__(THREADS) void sk_final(
        const uint2* __restrict__ K, const float* __restrict__ u,
        const float* __restrict__ csum_last, float* __restrict__ out) {
    const int t = threadIdx.x;
    const int row = blockIdx.x;
    const int b = blockIdx.y;
    const float ui = u[b * N + row];
    const float4 ci = ((const float4*)(csum_last + b * N))[t];
    const float4 vv = make_float4(1.0f / ci.x, 1.0f / ci.y, 1.0f / ci.z, 1.0f / ci.w);
    const size_t base = (size_t)b * N + row;
    float4 k = h4_to_f4((K + base * NU2)[t]);
    float4 o;
    o.x = k.x * ui * vv.x;
    o.y = k.y * ui * vv.y;
    o.z = k.z * ui * vv.z;
    o.w = k.w * ui * vv.w;
    ((float4*)(out + base * N))[t] = o;
}

// ---------- fallback all-fp32 path ----------

__device__ __forceinline__ float block_reduce_broadcast(float val, float* lds) {
    #pragma unroll
    for (int off = 32; off > 0; off >>= 1)
        val += __shfl_xor(val, off, 64);
    const int lane = threadIdx.x & 63;
    const int wid  = threadIdx.x >> 6;
    if (lane == 0) lds[wid] = val;
    __syncthreads();
    float total = lds[0] + lds[1] + lds[2] + lds[3];
    __syncthreads();
    return total;
}

__global__ __launch_bounds__(THREADS) void sink_init(float* __restrict__ v,
                                                     float* __restrict__ colsum) {
    const int i = blockIdx.x * THREADS + threadIdx.x;
    v[i] = 1.0f;
    colsum[i] = 0.0f;
}

__global__ __launch_bounds__(THREADS) void sink_iter(
        const float* __restrict__ C, const float* __restrict__ eps,
        const float* __restrict__ v, float* __restrict__ u,
        float* __restrict__ colsum) {
    __shared__ float lds[4];
    const int t = threadIdx.x;
    const int b = blockIdx.y;
    const int row0 = blockIdx.x * RPB;
    const float neg_inv_eps = -1.0f / eps[0];

    const float4 vv = ((const float4*)(v + b * N))[t];
    const float4* __restrict__ Cp = (const float4*)(C + ((size_t)b * N + row0) * N);

    float4 colacc = make_float4(0.f, 0.f, 0.f, 0.f);
    float4 cur = Cp[t];
    for (int i = 0; i < RPB; ++i) {
        float4 nxt = cur;
        if (i + 1 < RPB)
            nxt = Cp[(size_t)(i + 1) * (N / 4) + t];

        float4 k;
        k.x = __expf(cur.x * neg_inv_eps);
        k.y = __expf(cur.y * neg_inv_eps);
        k.z = __expf(cur.z * neg_inv_eps);
        k.w = __expf(cur.w * neg_inv_eps);

        float s = k.x * vv.x + k.y * vv.y + k.z * vv.z + k.w * vv.w;
        float S = block_reduce_broadcast(s, lds);
        float ui = 1.0f / S;
        if (t == 0) u[b * N + row0 + i] = ui;

        colacc.x += k.x * ui;
        colacc.y += k.y * ui;
        colacc.z += k.z * ui;
        colacc.w += k.w * ui;
        cur = nxt;
    }

    float* cs = colsum + b * N + 4 * t;
    atomicAdd(cs + 0, colacc.x);
    atomicAdd(cs + 1, colacc.y);
    atomicAdd(cs + 2, colacc.z);
    atomicAdd(cs + 3, colacc.w);
}

__global__ __launch_bounds__(THREADS) void sink_fix(float* __restrict__ v,
                                                    float* __restrict__ colsum) {
    const int i = blockIdx.x * THREADS + threadIdx.x;
    v[i] = 1.0f / colsum[i];
    colsum[i] = 0.0f;
}

__global__ __launch_bounds__(THREADS) void sink_final(
        const float* __restrict__ C, const float* __restrict__ eps,
        const float* __restrict__ u, const float* __restrict__ v,
        float* __restrict__ out) {
    const int t = threadIdx.x;
    const int row = blockIdx.x;
    const int b = blockIdx.y;
    const float neg_inv_eps = -1.0f / eps[0];
    const float ui = u[b * N + row];
    const float4 vv = ((const float4*)(v + b * N))[t];
    const size_t base = ((size_t)b * N + row) * N;
    float4 c = ((const float4*)(C + base))[t];
    float4 o;
    o.x = __expf(c.x * neg_inv_eps) * ui * vv.x;
    o.y = __expf(c.y * neg_inv_eps) * ui * vv.y;
    o.z = __expf(c.z * neg_inv_eps) * ui * vv.z;
    o.w = __expf(c.w * neg_inv_eps) * ui * vv.w;
    ((float4*)(out + base))[t] = o;
}

// ---------- launch ----------

extern "C" void kernel_launch(void* const* d_in, const int* in_sizes, int n_in,
                              void* d_out, int out_size, void* d_ws, size_t ws_size,
                              hipStream_t stream) {
    const float* C   = (const float*)d_in[0];
    const float* eps = (const float*)d_in[1];
    float* out = (float*)d_out;

    const size_t k16_bytes = (size_t)BATCH * N * N * 2;   // 134 MB
    const size_t k8_bytes  = (size_t)BATCH * N * N;       // 67 MB
    const size_t uv_elems  = (size_t)BATCH * N;           // 64K floats
    const size_t needed    = k16_bytes + k8_bytes +
                             (CSUM_ELEMS + BAR_WORDS + uv_elems) * 4;

    if (ws_size >= needed) {
        uint4* K16 = (uint4*)d_ws;
        uint4* K8  = (uint4*)((char*)d_ws + k16_bytes);
        float* csum = (float*)((char*)d_ws + k16_bytes + k8_bytes);
        unsigned* bar = (unsigned*)(csum + CSUM_ELEMS);
        float* u = (float*)(bar + BAR_WORDS);  // fallback path only

        // co-residency check for the persistent kernel (cached)
        static int coop_ok = -1;
        if (coop_ok < 0) {
            int nb = 0;
            hipError_t e = hipOccupancyMaxActiveBlocksPerMultiprocessor(
                &nb, sk_fused, THREADS, 0);
            coop_ok = (e == hipSuccess && nb >= 4) ? 1 : 0;
        }

        const int zero_total = (int)(CSUM_ELEMS + BAR_WORDS);
        sk_zero<<<dim3((zero_total + THREADS - 1) / THREADS), dim3(THREADS),
                  0, stream>>>(csum, zero_total);

        if (coop_ok) {
            sk_fused<<<dim3(NBLK), dim3(THREADS), 0, stream>>>(
                C, eps, K16, K8, csum, bar, out);
        } else {
            sk_build<<<dim3(BPB, BATCH), dim3(THREADS), 0, stream>>>(
                C, eps, K16, K8, u, csum);
            for (int it = 2; it <= NITERS - 1; ++it) {
                sk_iter8<<<dim3(BPB, BATCH), dim3(THREADS), 0, stream>>>(
                    K8, csum + (size_t)(it - 2) * uv_elems,
                    csum + (size_t)(it - 1) * uv_elems);
            }
            sk_iter<<<dim3(BPB, BATCH), dim3(THREADS), 0, stream>>>(
                K16, csum + (size_t)(NITERS - 2) * uv_elems, u,
                csum + (size_t)(NITERS - 1) * uv_elems);
            sk_final<<<dim3(N, BATCH), dim3(THREADS), 0, stream>>>(
                (const uint2*)K16, u, csum + (size_t)(NITERS - 1) * uv_elems, out);
        }
    } else {
        float* u      = (float*)d_ws;
        float* v      = u + uv_elems;
        float* colsum = v + uv_elems;
        sink_init<<<dim3(BATCH * N / THREADS), dim3(THREADS), 0, stream>>>(v, colsum);
        for (int it = 0; it < NITERS; ++it) {
            sink_iter<<<dim3(BPB, BATCH), dim3(THREADS), 0, stream>>>(
                C, eps, v, u, colsum);
            sink_fix<<<dim3(BATCH * N / THREADS), dim3(THREADS), 0, stream>>>(v, colsum);
        }
        sink_final<<<dim3(N, BATCH), dim3(THREADS), 0, stream>>>(C, eps, u, v, out);
    }
}